// Round 21
// baseline (388.920 us; speedup 1.0000x reference)
//
#include <hip/hip_runtime.h>

#define R_    16
#define NBAS  30
#define DIN1  128
#define DHID  128
#define DOUT2 64
#define DADR  400
#define KCH   128              // feature width of both layer inputs
#define NCHUNK 34              // 2 halves x (16 relations + root)

typedef __attribute__((ext_vector_type(8))) short bf16x8;
typedef __attribute__((ext_vector_type(4))) float f32x4;

__device__ __forceinline__ short f2bf(float f) {
    unsigned u = __float_as_uint(f);
    u += 0x7fffu + ((u >> 16) & 1u);   // round-to-nearest-even
    return (short)(u >> 16);
}
__device__ __forceinline__ unsigned packbf(float lo, float hi) {
    return (unsigned)(unsigned short)f2bf(lo) | ((unsigned)(unsigned short)f2bf(hi) << 16);
}

// 4-channel f32 accumulator (one 64-ch half-row is 16 lanes x 4 ch)
__device__ __forceinline__ f32x4 r4_add(f32x4 a, int2 v) {
    unsigned u0 = (unsigned)v.x, u1 = (unsigned)v.y;
    a[0] += __uint_as_float(u0 << 16);
    a[1] += __uint_as_float(u0 & 0xffff0000u);
    a[2] += __uint_as_float(u1 << 16);
    a[3] += __uint_as_float(u1 & 0xffff0000u);
    return a;
}
__device__ __forceinline__ int2 r4_pack(f32x4 a) {
    int2 o;
    o.x = (int)packbf(a[0], a[1]);
    o.y = (int)packbf(a[2], a[3]);
    return o;
}

// async 16B global -> LDS copy (dest = lds_uniform + lane*16)
__device__ __forceinline__ void gload_lds16(const void* g, void* l) {
    __builtin_amdgcn_global_load_lds(
        (const __attribute__((address_space(1))) unsigned int*)g,
        (__attribute__((address_space(3))) unsigned int*)l, 16, 0, 0);
}

// swizzled-image short index for a 64-ch chunk image: out-col o, in-ch k (0..63)
__device__ __forceinline__ int swz64(int o, int k) {
    int ib = ((o * 128 + ((k >> 3) << 4)) ^ ((o & 7) << 4)) + ((k & 7) << 1);
    return ib >> 1;
}

// gather-mean (64-ch half) using PRELOADED indices; lane holds 4 ch (int2).
__device__ __forceinline__ f32x4 gather4(const short* __restrict__ featbf,
                                         const int* __restrict__ srt,
                                         int b, int c, int idx, int l16, int hoff) {
    f32x4 a = (f32x4){0.f, 0.f, 0.f, 0.f};
    int s = c < 16 ? c : 16;
    int j = 0;
    for (; j + 4 <= s; j += 4) {
        int i0 = __shfl(idx, j, 16);
        int i1 = __shfl(idx, j + 1, 16);
        int i2 = __shfl(idx, j + 2, 16);
        int i3 = __shfl(idx, j + 3, 16);
        int2 v0 = *(const int2*)(featbf + (size_t)i0 * KCH + hoff + l16 * 4);
        int2 v1 = *(const int2*)(featbf + (size_t)i1 * KCH + hoff + l16 * 4);
        int2 v2 = *(const int2*)(featbf + (size_t)i2 * KCH + hoff + l16 * 4);
        int2 v3 = *(const int2*)(featbf + (size_t)i3 * KCH + hoff + l16 * 4);
        a = r4_add(a, v0); a = r4_add(a, v1);
        a = r4_add(a, v2); a = r4_add(a, v3);
    }
    for (; j + 2 <= s; j += 2) {
        int i0 = __shfl(idx, j, 16);
        int i1 = __shfl(idx, j + 1, 16);
        int2 v0 = *(const int2*)(featbf + (size_t)i0 * KCH + hoff + l16 * 4);
        int2 v1 = *(const int2*)(featbf + (size_t)i1 * KCH + hoff + l16 * 4);
        a = r4_add(a, v0); a = r4_add(a, v1);
    }
    if (j < s) {
        int i0 = __shfl(idx, j, 16);
        a = r4_add(a, *(const int2*)(featbf + (size_t)i0 * KCH + hoff + l16 * 4));
    }
    for (int p = b + 16; p < b + c; ++p)   // rare tail (>16 edges)
        a = r4_add(a, *(const int2*)(featbf + (size_t)srt[p] * KCH + hoff + l16 * 4));
    float sc = 1.f / (float)(c > 1 ? c : 1);
    a[0] *= sc; a[1] *= sc; a[2] *= sc; a[3] *= sc;
    return a;
}

// ------- fused setup: tobf + edge counts + weight prep (64-ch swizzled chunk images + wcT) -------
#define PREP1 (R_ * DIN1 * DHID)                    // 262144
#define PREP2 (PREP1 + R_ * DHID * DOUT2)           // +131072
#define PREP3 (PREP2 + DIN1 * DHID)                 // +16384
#define PREP4 (PREP3 + DHID * DOUT2)                // +8192
#define PREP5 (PREP4 + DADR * DOUT2)                // +25600
__global__ __launch_bounds__(256)
void setup_kernel(const float* __restrict__ x, short* __restrict__ xbf, int n4,
                  const int* __restrict__ dst, const int* __restrict__ ety,
                  int* __restrict__ cnt, int E, int N,
                  const float* __restrict__ comp1, const float* __restrict__ basis1,
                  const float* __restrict__ root1,
                  const float* __restrict__ comp2, const float* __restrict__ basis2,
                  const float* __restrict__ root2,
                  const float* __restrict__ wc,
                  short* __restrict__ BT1, short* __restrict__ BT2,
                  short* __restrict__ wcT) {
    int gid = blockIdx.x * 256 + threadIdx.x;
    if (gid < n4) {
        float4 v = ((const float4*)x)[gid];
        short4 b = { f2bf(v.x), f2bf(v.y), f2bf(v.z), f2bf(v.w) };
        ((short4*)xbf)[gid] = b;
        return;
    }
    gid -= n4;
    if (gid < E) {
        atomicAdd(&cnt[ety[gid] * N + dst[gid]], 1);
        return;
    }
    int idx = gid - E;
    if (idx < PREP1) {
        int o = idx % DHID, i = (idx / DHID) % DIN1, r = idx / (DHID * DIN1);
        float acc = 0.f;
        #pragma unroll 6
        for (int b = 0; b < NBAS; ++b)
            acc += comp1[r * NBAS + b] * basis1[((size_t)b * DIN1 + i) * DHID + o];
        int c = (i >> 6) * 17 + r;
        BT1[(size_t)c * (DHID * 64) + swz64(o, i & 63)] = f2bf(acc);
    } else if (idx < PREP2) {
        int t = idx - PREP1;
        int o = t % DOUT2, i = (t / DOUT2) % DHID, r = t / (DOUT2 * DHID);
        float acc = 0.f;
        #pragma unroll 6
        for (int b = 0; b < NBAS; ++b)
            acc += comp2[r * NBAS + b] * basis2[((size_t)b * DHID + i) * DOUT2 + o];
        int c = (i >> 6) * 17 + r;
        BT2[(size_t)c * (DOUT2 * 64) + swz64(o, i & 63)] = f2bf(acc);
    } else if (idx < PREP3) {
        int t = idx - PREP2;
        int o = t % DHID, i = t / DHID;
        int c = (i >> 6) * 17 + R_;
        BT1[(size_t)c * (DHID * 64) + swz64(o, i & 63)] = f2bf(root1[(size_t)i * DHID + o]);
    } else if (idx < PREP4) {
        int t = idx - PREP3;
        int o = t % DOUT2, i = t / DOUT2;
        int c = (i >> 6) * 17 + R_;
        BT2[(size_t)c * (DOUT2 * 64) + swz64(o, i & 63)] = f2bf(root2[(size_t)i * DOUT2 + o]);
    } else if (idx < PREP5) {
        int t = idx - PREP4;
        int a = t / DOUT2, k = t % DOUT2;
        wcT[(size_t)a * DOUT2 + k] = f2bf(wc[(size_t)k * DADR + a]);
    }
}

// ---------------- 3-phase exclusive scan over nseg counts ----------------
#define SCAN_CHUNK 2048
#define SCAN_IT    8

__global__ __launch_bounds__(256) void scan_bsum_kernel(const int* __restrict__ cnt, int nseg,
                                                        int* __restrict__ bsum) {
    __shared__ int sd[256];
    int base = blockIdx.x * SCAN_CHUNK;
    int s = 0;
    #pragma unroll
    for (int j = 0; j < SCAN_IT; ++j) {
        int idx = base + j * 256 + threadIdx.x;
        if (idx < nseg) s += cnt[idx];
    }
    sd[threadIdx.x] = s;
    __syncthreads();
    for (int st = 128; st > 0; st >>= 1) {
        if (threadIdx.x < st) sd[threadIdx.x] += sd[threadIdx.x + st];
        __syncthreads();
    }
    if (threadIdx.x == 0) bsum[blockIdx.x] = sd[0];
}

__global__ __launch_bounds__(256) void scan_top_kernel(const int* __restrict__ bsum, int nblk,
                                                       int* __restrict__ boff,
                                                       int* __restrict__ off, int nseg) {
    if (nblk > 256) {
        if (threadIdx.x == 0) {
            int run = 0;
            for (int i = 0; i < nblk; ++i) { int t = bsum[i]; boff[i] = run; run += t; }
            off[nseg] = run;
        }
        return;
    }
    __shared__ int sd[256];
    int v = (threadIdx.x < nblk) ? bsum[threadIdx.x] : 0;
    sd[threadIdx.x] = v;
    __syncthreads();
    for (int st = 1; st < 256; st <<= 1) {
        int t = (threadIdx.x >= st) ? sd[threadIdx.x - st] : 0;
        __syncthreads();
        sd[threadIdx.x] += t;
        __syncthreads();
    }
    if (threadIdx.x < nblk) boff[threadIdx.x] = sd[threadIdx.x] - v;   // exclusive
    if (threadIdx.x == nblk - 1) off[nseg] = sd[threadIdx.x];          // total = E
}

__global__ __launch_bounds__(256) void scan_final_kernel(const int* __restrict__ cnt, int nseg,
                                                         const int* __restrict__ boff,
                                                         int* __restrict__ off,
                                                         int* __restrict__ cursor) {
    __shared__ int sd[256];
    int base = blockIdx.x * SCAN_CHUNK + threadIdx.x * SCAN_IT;
    int v[SCAN_IT];
    int s = 0;
    #pragma unroll
    for (int j = 0; j < SCAN_IT; ++j) {
        int idx = base + j;
        v[j] = (idx < nseg) ? cnt[idx] : 0;
        s += v[j];
    }
    sd[threadIdx.x] = s;
    __syncthreads();
    for (int st = 1; st < 256; st <<= 1) {
        int t = (threadIdx.x >= st) ? sd[threadIdx.x - st] : 0;
        __syncthreads();
        sd[threadIdx.x] += t;
        __syncthreads();
    }
    int run = boff[blockIdx.x] + sd[threadIdx.x] - s;
    #pragma unroll
    for (int j = 0; j < SCAN_IT; ++j) {
        int idx = base + j;
        if (idx < nseg) { off[idx] = run; cursor[idx] = run; }
        run += v[j];
    }
}

// ---------------- bucket the source indices (CSR payload, (r,dst)-major) ----------------
__global__ __launch_bounds__(256) void reorder_kernel(const int* __restrict__ src,
                                                      const int* __restrict__ dst,
                                                      const int* __restrict__ ety,
                                                      int* __restrict__ cursor,
                                                      int* __restrict__ srt, int E, int N) {
    int e = blockIdx.x * blockDim.x + threadIdx.x;
    if (e >= E) return;
    int seg = ety[e] * N + dst[e];
    int pos = atomicAdd(&cursor[seg], 1);
    srt[pos] = src[e];
}

// ------- FUSED RGCN layer (round-19 pipeline, channel-halved for L2 residency):
//   256 thr / 4 waves, BM=32, 2 rows per 16-lane group. 34 chunks of BK=64:
//   t = h*17 + r (h = channel half, r = relation, r=16 -> root as c=1 bucket).
//   During each half-phase the gather working set is N x 128B = 3.84 MB ->
//   fits per-XCD L2. Per chunk: b1 -> async-stage B image (0 VGPR) ->
//   prefetch idx t+1 -> gather half-row pair -> write lA -> b2 -> MFMA. -------
template<int BN, bool OUTBF>
__global__ __launch_bounds__(256, 4)
void rgcn_fused_kernel(const short* __restrict__ featbf,   // [N][128] bf16
                       const int* __restrict__ off2,       // [R_*N+1] CSR offsets (r-major)
                       const int* __restrict__ srt,        // [E] src indices
                       const short* __restrict__ BT,       // 34 swizzled 64-ch chunk images
                       const float* __restrict__ bias,
                       void* __restrict__ Hout, int N, int relu)
{
    constexpr int BM = 32;
    constexpr int WN = BN / 4;       // 32 (BN=128) or 16 (BN=64)
    constexpr int MR = 2;
    constexpr int NR = WN / 16;      // 2 or 1
    constexpr int NCOPY = BN / 32;   // async 4KB copies per chunk image (4 or 2)

    __shared__ short lA[BM * 64];    // 4 KB (BK=64)
    __shared__ short lB[BN * 64];    // 16 / 8 KB

    const int tid  = threadIdx.x;
    const int lane = tid & 63;
    const int wv   = tid >> 6;       // wave = column group
    const int g16  = tid >> 4;       // 16 groups of 16 lanes
    const int l16  = tid & 15;       // int2 slot within 64-bf16 half-row
    const int n0   = blockIdx.x * BM;
    const int row0 = n0 + g16;
    const int row1 = n0 + 16 + g16;

    f32x4 acc[MR][NR];
    #pragma unroll
    for (int m = 0; m < MR; ++m)
        #pragma unroll
        for (int n = 0; n < NR; ++n)
            acc[m][n] = (f32x4){0.f, 0.f, 0.f, 0.f};

    // ---- lane r holds segment bounds of relation r for both rows ----
    int b0v = 0, e0v = 0, b1v = 0, e1v = 0;
    if (row0 < N) { b0v = off2[l16 * N + row0]; e0v = off2[l16 * N + row0 + 1]; }
    if (row1 < N) { b1v = off2[l16 * N + row1]; e1v = off2[l16 * N + row1 + 1]; }

    // chunk 0 (h=0, r=0) bounds + index vectors
    int cb0 = __shfl(b0v, 0, 16), cc0 = __shfl(e0v, 0, 16) - cb0;
    int cb1 = __shfl(b1v, 0, 16), cc1 = __shfl(e1v, 0, 16) - cb1;
    int cidx0 = (l16 < (cc0 < 16 ? cc0 : 16)) ? srt[cb0 + l16] : 0;
    int cidx1 = (l16 < (cc1 < 16 ? cc1 : 16)) ? srt[cb1 + l16] : 0;

    for (int t = 0; t < NCHUNK; ++t) {
        __syncthreads();              // b1: previous MFMA reads done; lA/lB free

        // ---- 1. async-stage B chunk image t (zero VGPR cost) ----
        {
            const char* srcB = (const char*)BT + (size_t)t * BN * 128;
            #pragma unroll
            for (int j = 0; j < NCOPY; ++j) {
                const char* g = srcB + j * 4096 + wv * 1024 + (lane << 4);
                char* l = (char*)lB + j * 4096 + wv * 1024;
                gload_lds16(g, l);
            }
        }

        // ---- 2. prefetch next chunk's bounds + srt indices ----
        int nb0 = 0, nc0 = 0, nidx0 = 0, nb1 = 0, nc1 = 0, nidx1 = 0;
        if (t + 1 < NCHUNK) {
            int rn = (t + 1) % 17;
            if (rn < R_) {
                nb0 = __shfl(b0v, rn, 16); nc0 = __shfl(e0v, rn, 16) - nb0;
                nb1 = __shfl(b1v, rn, 16); nc1 = __shfl(e1v, rn, 16) - nb1;
                nidx0 = (l16 < (nc0 < 16 ? nc0 : 16)) ? srt[nb0 + l16] : 0;
                nidx1 = (l16 < (nc1 < 16 ? nc1 : 16)) ? srt[nb1 + l16] : 0;
            } else {                  // root: bucket of size 1, idx = row
                nc0 = (row0 < N) ? 1 : 0; nidx0 = (row0 < N) ? row0 : 0;
                nc1 = (row1 < N) ? 1 : 0; nidx1 = (row1 < N) ? row1 : 0;
            }
        }

        // ---- 3. gather current chunk (64-ch half; only feat loads on chain) ----
        const int hoff = (t < 17) ? 0 : 64;
        f32x4 a0 = gather4(featbf, srt, cb0, cc0, cidx0, l16, hoff);
        f32x4 a1 = gather4(featbf, srt, cb1, cc1, cidx1, l16, hoff);

        // ---- 4. write A half-rows to LDS (swizzled, 8B per lane) ----
        {
            int byte0 = (g16 * 128 + (((l16 >> 1) << 4) ^ ((g16 & 7) << 4))) + ((l16 & 1) << 3);
            *(int2*)((char*)lA + byte0) = r4_pack(a0);
            int rowl = 16 + g16;
            int byte1 = (rowl * 128 + (((l16 >> 1) << 4) ^ ((rowl & 7) << 4))) + ((l16 & 1) << 3);
            *(int2*)((char*)lA + byte1) = r4_pack(a1);
        }
        __syncthreads();              // b2: lA published, async B landed (vmcnt drain)

        // ---- 5. MFMA chunk t (BK=64: 2 K-steps) ----
        #pragma unroll
        for (int kk = 0; kk < 2; ++kk) {
            const int u = kk * 4 + (lane >> 4);      // 16B unit within 128B row
            bf16x8 af[MR], bfr[NR];
            #pragma unroll
            for (int m = 0; m < MR; ++m) {
                int row = m * 16 + (lane & 15);
                af[m] = *(const bf16x8*)((const char*)lA +
                         row * 128 + ((u << 4) ^ ((row & 7) << 4)));
            }
            #pragma unroll
            for (int n = 0; n < NR; ++n) {
                int col = wv * WN + n * 16 + (lane & 15);
                bfr[n] = *(const bf16x8*)((const char*)lB +
                         col * 128 + ((u << 4) ^ ((col & 7) << 4)));
            }
            #pragma unroll
            for (int m = 0; m < MR; ++m)
                #pragma unroll
                for (int n = 0; n < NR; ++n)
                    acc[m][n] = __builtin_amdgcn_mfma_f32_16x16x32_bf16(
                        af[m], bfr[n], acc[m][n], 0, 0, 0);
        }

        // ---- 6. rotate prefetched index state ----
        cb0 = nb0; cc0 = nc0; cidx0 = nidx0;
        cb1 = nb1; cc1 = nc1; cidx1 = nidx1;
    }

    // ---- epilogue: C/D layout row=(lane>>4)*4+i, col=lane&15 ----
    #pragma unroll
    for (int m = 0; m < MR; ++m)
        #pragma unroll
        for (int n = 0; n < NR; ++n)
            #pragma unroll
            for (int i = 0; i < 4; ++i) {
                int row  = m * 16 + ((lane >> 4) << 2) + i;
                int col  = wv * WN + n * 16 + (lane & 15);
                int grow = n0 + row;
                if (grow >= N) continue;
                float v = acc[m][n][i] + bias[col];
                if (relu) v = fmaxf(v, 0.f);
                if (OUTBF) ((short*)Hout)[(size_t)grow * BN + col] = f2bf(v);
                else       ((float*)Hout)[(size_t)grow * BN + col] = v;
            }
}

// ------- classifier MFMA GEMM: out[n][a] = h2[n][:] @ wcT[a][:] + bc[a] -------
__global__ __launch_bounds__(256)
void classifier_gemm_kernel(const short* __restrict__ h2bf,   // [N][64] bf16
                            const short* __restrict__ wcT,    // [400][64] bf16
                            const float* __restrict__ bc,
                            float* __restrict__ out, int N)
{
    constexpr int BM = 128, BN = 80, BK = 64;
    constexpr int MR = 2, NR = 5;

    __shared__ short lA[BM * BK];
    __shared__ short lB[BN * BK];

    const int tid  = threadIdx.x;
    const int lane = tid & 63;
    const int wv   = tid >> 6;
    const int nodeBase = blockIdx.x * BM;
    const int colBase  = blockIdx.y * BN;

    const int t8  = tid & 7;
    const int r32 = tid >> 3;

    #pragma unroll
    for (int it = 0; it < 4; ++it) {
        int row  = it * 32 + r32;
        int grow = nodeBase + row;
        int4 v = {0, 0, 0, 0};
        if (grow < N) v = *(const int4*)(h2bf + (size_t)grow * DOUT2 + t8 * 8);
        int byte = ((row * BK + t8 * 8) << 1) ^ ((row & 7) << 4);
        *(int4*)((char*)lA + byte) = v;
    }
    for (int o = r32; o < BN; o += 32) {
        int4 v = *(const int4*)(wcT + (size_t)(colBase + o) * DOUT2 + t8 * 8);
        int byte = ((o * BK + t8 * 8) << 1) ^ ((o & 7) << 4);
        *(int4*)((char*)lB + byte) = v;
    }
    __syncthreads();

    f32x4 acc[MR][NR];
    #pragma unroll
    for (int m = 0; m < MR; ++m)
        #pragma unroll
        for (int n = 0; n < NR; ++n)
            acc[m][n] = (f32x4){0.f, 0.f, 0.f, 0.f};

    #pragma unroll
    for (int kk = 0; kk < BK / 32; ++kk) {
        const int kpos = kk * 32 + (lane >> 4) * 8;
        bf16x8 af[MR], bfr[NR];
        #pragma unroll
        for (int m = 0; m < MR; ++m) {
            int row = wv * 32 + m * 16 + (lane & 15);
            af[m] = *(const bf16x8*)((const char*)lA +
                     (((row * BK + kpos) << 1) ^ ((row & 7) << 4)));
        }
        #pragma unroll
        for (int n = 0; n < NR; ++n) {
            int col = n * 16 + (lane & 15);
            bfr[n] = *(const bf16x8*)((const char*)lB +
                     (((col * BK + kpos) << 1) ^ ((col & 7) << 4)));
        }
        #pragma unroll
        for (int m = 0; m < MR; ++m)
            #pragma unroll
            for (int n = 0; n < NR; ++n)
                acc[m][n] = __builtin_amdgcn_mfma_f32_16x16x32_bf16(
                    af[m], bfr[n], acc[m][n], 0, 0, 0);
    }

    #pragma unroll
    for (int m = 0; m < MR; ++m)
        #pragma unroll
        for (int n = 0; n < NR; ++n)
            #pragma unroll
            for (int i = 0; i < 4; ++i) {
                int row  = wv * 32 + m * 16 + ((lane >> 4) << 2) + i;
                int col  = n * 16 + (lane & 15);
                int grow = nodeBase + row;
                if (grow >= N) continue;
                int gcol = colBase + col;
                out[(size_t)grow * DADR + gcol] = acc[m][n][i] + bc[gcol];
            }
}

static inline size_t align16(size_t x) { return (x + 15) & ~(size_t)15; }

extern "C" void kernel_launch(void* const* d_in, const int* in_sizes, int n_in,
                              void* d_out, int out_size, void* d_ws, size_t ws_size,
                              hipStream_t stream) {
    const float* x      = (const float*)d_in[0];
    const int*   ei     = (const int*)d_in[1];
    const int*   et     = (const int*)d_in[2];
    const float* comp1  = (const float*)d_in[3];
    const float* basis1 = (const float*)d_in[4];
    const float* root1  = (const float*)d_in[5];
    const float* bias1  = (const float*)d_in[6];
    const float* comp2  = (const float*)d_in[7];
    const float* basis2 = (const float*)d_in[8];
    const float* root2  = (const float*)d_in[9];
    const float* bias2  = (const float*)d_in[10];
    const float* wc     = (const float*)d_in[11];
    const float* bc     = (const float*)d_in[12];
    float* out = (float*)d_out;

    const int E = in_sizes[1] / 2;
    const int N = in_sizes[0] / DIN1;
    const int* srcp = ei;
    const int* dstp = ei + E;

    const int NSEG = N * R_;
    const int NBLK = (NSEG + SCAN_CHUNK - 1) / SCAN_CHUNK;

    char* ws = (char*)d_ws;
    size_t o = 0;
    int*   cntI   = (int*)(ws + o);   o = align16(o + (size_t)NSEG * 4);
    int*   off2   = (int*)(ws + o);   o = align16(o + (size_t)(NSEG + 1) * 4);
    int*   cursor = (int*)(ws + o);   o = align16(o + (size_t)NSEG * 4);
    int*   bsum   = (int*)(ws + o);   o = align16(o + (size_t)NBLK * 4);
    int*   boff   = (int*)(ws + o);   o = align16(o + (size_t)NBLK * 4);
    int*   srt    = (int*)(ws + o);   o = align16(o + (size_t)E * 4);
    short* BT1    = (short*)(ws + o); o = align16(o + (size_t)NCHUNK * DHID * 64 * 2);
    short* BT2    = (short*)(ws + o); o = align16(o + (size_t)NCHUNK * DOUT2 * 64 * 2);
    short* wcTb   = (short*)(ws + o); o = align16(o + (size_t)DADR * DOUT2 * 2);
    short* xbf    = (short*)(ws + o); o = align16(o + (size_t)N * DIN1 * 2);
    short* h1bf   = (short*)(ws + o); o = align16(o + (size_t)N * DHID * 2);
    short* h2bf   = (short*)(ws + o); o = align16(o + (size_t)N * DOUT2 * 2);

    // ---- fused setup: tobf + counts + weight prep ----
    const int n4 = N * DIN1 / 4;
    hipMemsetAsync(cntI, 0, (size_t)NSEG * 4, stream);
    {
        long long total = (long long)n4 + E + PREP5;
        int grid = (int)((total + 255) / 256);
        setup_kernel<<<grid, 256, 0, stream>>>(x, xbf, n4, dstp, et, cntI, E, N,
                                               comp1, basis1, root1,
                                               comp2, basis2, root2, wc,
                                               BT1, BT2, wcTb);
    }

    // ---- CSR scan + reorder ----
    scan_bsum_kernel<<<NBLK, 256, 0, stream>>>(cntI, NSEG, bsum);
    scan_top_kernel<<<1, 256, 0, stream>>>(bsum, NBLK, boff, off2, NSEG);
    scan_final_kernel<<<NBLK, 256, 0, stream>>>(cntI, NSEG, boff, off2, cursor);
    reorder_kernel<<<(E + 255) / 256, 256, 0, stream>>>(srcp, dstp, et, cursor, srt, E, N);

    // ---- two fused RGCN layers ----
    const int gGrid = (N + 31) / 32;
    rgcn_fused_kernel<DHID, true><<<gGrid, 256, 0, stream>>>(xbf,  off2, srt, BT1, bias1, h1bf, N, 1);
    rgcn_fused_kernel<DOUT2, true><<<gGrid, 256, 0, stream>>>(h1bf, off2, srt, BT2, bias2, h2bf, N, 0);

    // ---- classifier (MFMA) ----
    dim3 cGrid((N + 127) / 128, DADR / 80);
    classifier_gemm_kernel<<<cGrid, 256, 0, stream>>>(h2bf, wcTb, bc, out, N);
}

// Round 22
// 295.448 us; speedup vs baseline: 1.3164x; 1.3164x over previous
//
#include <hip/hip_runtime.h>

#define R_    16
#define NBAS  30
#define DIN1  128
#define DHID  128
#define DOUT2 64
#define DADR  400
#define KCH   128              // feature width of both layer inputs

typedef __attribute__((ext_vector_type(8))) short bf16x8;
typedef __attribute__((ext_vector_type(4))) float f32x4;

__device__ __forceinline__ short f2bf(float f) {
    unsigned u = __float_as_uint(f);
    u += 0x7fffu + ((u >> 16) & 1u);   // round-to-nearest-even
    return (short)(u >> 16);
}
__device__ __forceinline__ unsigned packbf(float lo, float hi) {
    return (unsigned)(unsigned short)f2bf(lo) | ((unsigned)(unsigned short)f2bf(hi) << 16);
}

struct Row8 { f32x4 lo, hi; };

__device__ __forceinline__ Row8 row8_zero() {
    Row8 z; z.lo = (f32x4){0.f,0.f,0.f,0.f}; z.hi = (f32x4){0.f,0.f,0.f,0.f}; return z;
}
__device__ __forceinline__ Row8 row8_add(Row8 a, int4 v) {
    unsigned u0 = (unsigned)v.x, u1 = (unsigned)v.y, u2 = (unsigned)v.z, u3 = (unsigned)v.w;
    a.lo[0] += __uint_as_float(u0 << 16);
    a.lo[1] += __uint_as_float(u0 & 0xffff0000u);
    a.lo[2] += __uint_as_float(u1 << 16);
    a.lo[3] += __uint_as_float(u1 & 0xffff0000u);
    a.hi[0] += __uint_as_float(u2 << 16);
    a.hi[1] += __uint_as_float(u2 & 0xffff0000u);
    a.hi[2] += __uint_as_float(u3 << 16);
    a.hi[3] += __uint_as_float(u3 & 0xffff0000u);
    return a;
}
__device__ __forceinline__ int4 row8_pack(Row8 a) {
    int4 o;
    o.x = (int)packbf(a.lo[0], a.lo[1]);
    o.y = (int)packbf(a.lo[2], a.lo[3]);
    o.z = (int)packbf(a.hi[0], a.hi[1]);
    o.w = (int)packbf(a.hi[2], a.hi[3]);
    return o;
}

// async 16B global -> LDS copy (dest = lds_uniform + lane*16)
__device__ __forceinline__ void gload_lds16(const void* g, void* l) {
    __builtin_amdgcn_global_load_lds(
        (const __attribute__((address_space(1))) unsigned int*)g,
        (__attribute__((address_space(3))) unsigned int*)l, 16, 0, 0);
}

// swizzled-image short index for B element (chunk r, out-col o, in-ch k)
__device__ __forceinline__ size_t swzidx(int r, int o, int k, int chStride) {
    int ib = ((o * 256 + ((k >> 3) << 4)) ^ ((o & 15) << 4)) + ((k & 7) << 1);
    return (size_t)r * chStride + (ib >> 1);
}

// gather-mean using PRELOADED indices (idx = srt[b+l16], broadcast via shfl).
__device__ __forceinline__ Row8 gather_idx(const short* __restrict__ featbf,
                                           const int* __restrict__ srt,
                                           int b, int c, int idx, int l16) {
    Row8 a = row8_zero();
    int s = c < 16 ? c : 16;
    int j = 0;
    for (; j + 4 <= s; j += 4) {
        int i0 = __shfl(idx, j, 16);
        int i1 = __shfl(idx, j + 1, 16);
        int i2 = __shfl(idx, j + 2, 16);
        int i3 = __shfl(idx, j + 3, 16);
        int4 v0 = *(const int4*)(featbf + (size_t)i0 * KCH + l16 * 8);
        int4 v1 = *(const int4*)(featbf + (size_t)i1 * KCH + l16 * 8);
        int4 v2 = *(const int4*)(featbf + (size_t)i2 * KCH + l16 * 8);
        int4 v3 = *(const int4*)(featbf + (size_t)i3 * KCH + l16 * 8);
        a = row8_add(a, v0); a = row8_add(a, v1);
        a = row8_add(a, v2); a = row8_add(a, v3);
    }
    for (; j + 2 <= s; j += 2) {
        int i0 = __shfl(idx, j, 16);
        int i1 = __shfl(idx, j + 1, 16);
        int4 v0 = *(const int4*)(featbf + (size_t)i0 * KCH + l16 * 8);
        int4 v1 = *(const int4*)(featbf + (size_t)i1 * KCH + l16 * 8);
        a = row8_add(a, v0); a = row8_add(a, v1);
    }
    if (j < s) {
        int i0 = __shfl(idx, j, 16);
        a = row8_add(a, *(const int4*)(featbf + (size_t)i0 * KCH + l16 * 8));
    }
    for (int p = b + 16; p < b + c; ++p)   // rare tail (>16 edges)
        a = row8_add(a, *(const int4*)(featbf + (size_t)srt[p] * KCH + l16 * 8));
    float sc = 1.f / (float)(c > 1 ? c : 1);
    a.lo *= sc; a.hi *= sc;
    return a;
}

// ------- fused setup: tobf (x->bf16) + edge counts + weight prep (swizzled images + wcT) -------
#define PREP1 (R_ * DIN1 * DHID)                    // 262144
#define PREP2 (PREP1 + R_ * DHID * DOUT2)           // +131072
#define PREP3 (PREP2 + DIN1 * DHID)                 // +16384
#define PREP4 (PREP3 + DHID * DOUT2)                // +8192
#define PREP5 (PREP4 + DADR * DOUT2)                // +25600
__global__ __launch_bounds__(256)
void setup_kernel(const float* __restrict__ x, short* __restrict__ xbf, int n4,
                  const int* __restrict__ dst, const int* __restrict__ ety,
                  int* __restrict__ cnt, int E, int N,
                  const float* __restrict__ comp1, const float* __restrict__ basis1,
                  const float* __restrict__ root1,
                  const float* __restrict__ comp2, const float* __restrict__ basis2,
                  const float* __restrict__ root2,
                  const float* __restrict__ wc,
                  short* __restrict__ BT1, short* __restrict__ BT2,
                  short* __restrict__ wcT) {
    int gid = blockIdx.x * 256 + threadIdx.x;
    if (gid < n4) {
        float4 v = ((const float4*)x)[gid];
        short4 b = { f2bf(v.x), f2bf(v.y), f2bf(v.z), f2bf(v.w) };
        ((short4*)xbf)[gid] = b;
        return;
    }
    gid -= n4;
    if (gid < E) {
        atomicAdd(&cnt[ety[gid] * N + dst[gid]], 1);
        return;
    }
    int idx = gid - E;
    if (idx < PREP1) {
        int o = idx % DHID, i = (idx / DHID) % DIN1, r = idx / (DHID * DIN1);
        float acc = 0.f;
        #pragma unroll 6
        for (int b = 0; b < NBAS; ++b)
            acc += comp1[r * NBAS + b] * basis1[((size_t)b * DIN1 + i) * DHID + o];
        BT1[swzidx(r, o, i, DHID * 128)] = f2bf(acc);
    } else if (idx < PREP2) {
        int t = idx - PREP1;
        int o = t % DOUT2, i = (t / DOUT2) % DHID, r = t / (DOUT2 * DHID);
        float acc = 0.f;
        #pragma unroll 6
        for (int b = 0; b < NBAS; ++b)
            acc += comp2[r * NBAS + b] * basis2[((size_t)b * DHID + i) * DOUT2 + o];
        BT2[swzidx(r, o, i, DOUT2 * 128)] = f2bf(acc);
    } else if (idx < PREP3) {
        int t = idx - PREP2;
        int o = t % DHID, i = t / DHID;
        BT1[swzidx(R_, o, i, DHID * 128)] = f2bf(root1[(size_t)i * DHID + o]);
    } else if (idx < PREP4) {
        int t = idx - PREP3;
        int o = t % DOUT2, i = t / DOUT2;
        BT2[swzidx(R_, o, i, DOUT2 * 128)] = f2bf(root2[(size_t)i * DOUT2 + o]);
    } else if (idx < PREP5) {
        int t = idx - PREP4;
        int a = t / DOUT2, k = t % DOUT2;
        wcT[(size_t)a * DOUT2 + k] = f2bf(wc[(size_t)k * DADR + a]);
    }
}

// ---------------- 3-phase exclusive scan over nseg counts ----------------
#define SCAN_CHUNK 2048
#define SCAN_IT    8

__global__ __launch_bounds__(256) void scan_bsum_kernel(const int* __restrict__ cnt, int nseg,
                                                        int* __restrict__ bsum) {
    __shared__ int sd[256];
    int base = blockIdx.x * SCAN_CHUNK;
    int s = 0;
    #pragma unroll
    for (int j = 0; j < SCAN_IT; ++j) {
        int idx = base + j * 256 + threadIdx.x;
        if (idx < nseg) s += cnt[idx];
    }
    sd[threadIdx.x] = s;
    __syncthreads();
    for (int st = 128; st > 0; st >>= 1) {
        if (threadIdx.x < st) sd[threadIdx.x] += sd[threadIdx.x + st];
        __syncthreads();
    }
    if (threadIdx.x == 0) bsum[blockIdx.x] = sd[0];
}

__global__ __launch_bounds__(256) void scan_top_kernel(const int* __restrict__ bsum, int nblk,
                                                       int* __restrict__ boff,
                                                       int* __restrict__ off, int nseg) {
    if (nblk > 256) {
        if (threadIdx.x == 0) {
            int run = 0;
            for (int i = 0; i < nblk; ++i) { int t = bsum[i]; boff[i] = run; run += t; }
            off[nseg] = run;
        }
        return;
    }
    __shared__ int sd[256];
    int v = (threadIdx.x < nblk) ? bsum[threadIdx.x] : 0;
    sd[threadIdx.x] = v;
    __syncthreads();
    for (int st = 1; st < 256; st <<= 1) {
        int t = (threadIdx.x >= st) ? sd[threadIdx.x - st] : 0;
        __syncthreads();
        sd[threadIdx.x] += t;
        __syncthreads();
    }
    if (threadIdx.x < nblk) boff[threadIdx.x] = sd[threadIdx.x] - v;   // exclusive
    if (threadIdx.x == nblk - 1) off[nseg] = sd[threadIdx.x];          // total = E
}

__global__ __launch_bounds__(256) void scan_final_kernel(const int* __restrict__ cnt, int nseg,
                                                         const int* __restrict__ boff,
                                                         int* __restrict__ off,
                                                         int* __restrict__ cursor) {
    __shared__ int sd[256];
    int base = blockIdx.x * SCAN_CHUNK + threadIdx.x * SCAN_IT;
    int v[SCAN_IT];
    int s = 0;
    #pragma unroll
    for (int j = 0; j < SCAN_IT; ++j) {
        int idx = base + j;
        v[j] = (idx < nseg) ? cnt[idx] : 0;
        s += v[j];
    }
    sd[threadIdx.x] = s;
    __syncthreads();
    for (int st = 1; st < 256; st <<= 1) {
        int t = (threadIdx.x >= st) ? sd[threadIdx.x - st] : 0;
        __syncthreads();
        sd[threadIdx.x] += t;
        __syncthreads();
    }
    int run = boff[blockIdx.x] + sd[threadIdx.x] - s;
    #pragma unroll
    for (int j = 0; j < SCAN_IT; ++j) {
        int idx = base + j;
        if (idx < nseg) { off[idx] = run; cursor[idx] = run; }
        run += v[j];
    }
}

// ---------------- bucket the source indices (CSR payload, (r,dst)-major) ----------------
__global__ __launch_bounds__(256) void reorder_kernel(const int* __restrict__ src,
                                                      const int* __restrict__ dst,
                                                      const int* __restrict__ ety,
                                                      int* __restrict__ cursor,
                                                      int* __restrict__ srt, int E, int N) {
    int e = blockIdx.x * blockDim.x + threadIdx.x;
    if (e >= E) return;
    int seg = ety[e] * N + dst[e];
    int pos = atomicAdd(&cursor[seg], 1);
    srt[pos] = src[e];
}

// ------- FUSED RGCN layer (B staged via global_load_lds, index pipelining):
//   256 thr / 4 waves, BM=32, 2 rows per 16-lane group. Per chunk r:
//   b1 -> issue async B stage (no VGPRs) -> prefetch idx r+1 -> gather r ->
//   write lA -> b2 (drains vmcnt: B landed) -> MFMA. B source is a
//   pre-swizzled per-chunk image so the linear async copy reproduces the
//   swizzled LDS layout. -------
template<int BN, bool OUTBF>
__global__ __launch_bounds__(256, 4)
void rgcn_fused_kernel(const short* __restrict__ featbf,   // [N][128] bf16
                       const int* __restrict__ off2,       // [R_*N+1] CSR offsets (r-major)
                       const int* __restrict__ srt,        // [E] src indices
                       const short* __restrict__ BT,       // swizzled chunk images
                       const float* __restrict__ bias,
                       void* __restrict__ Hout, int N, int relu)
{
    constexpr int BM = 32, BK = 128;
    constexpr int WN = BN / 4;       // 32 (BN=128) or 16 (BN=64)
    constexpr int MR = 2;
    constexpr int NR = WN / 16;      // 2 or 1
    constexpr int NCOPY = BN / 16;   // async 4KB copies per chunk (8 or 4)

    __shared__ short lA[BM * BK];
    __shared__ short lB[BN * BK];

    const int tid  = threadIdx.x;
    const int lane = tid & 63;
    const int wv   = tid >> 6;       // wave = column group
    const int g16  = tid >> 4;       // 16 groups of 16 lanes
    const int l16  = tid & 15;       // int4 slot within 128-bf16 row
    const int n0   = blockIdx.x * BM;
    const int row0 = n0 + g16;
    const int row1 = n0 + 16 + g16;

    f32x4 acc[MR][NR];
    #pragma unroll
    for (int m = 0; m < MR; ++m)
        #pragma unroll
        for (int n = 0; n < NR; ++n)
            acc[m][n] = (f32x4){0.f, 0.f, 0.f, 0.f};

    // ---- lane r holds segment bounds of relation r for both rows ----
    int b0v = 0, e0v = 0, b1v = 0, e1v = 0;
    if (row0 < N) { b0v = off2[l16 * N + row0]; e0v = off2[l16 * N + row0 + 1]; }
    if (row1 < N) { b1v = off2[l16 * N + row1]; e1v = off2[l16 * N + row1 + 1]; }

    // current chunk (0) bounds + index vectors
    int cb0 = __shfl(b0v, 0, 16), cc0 = __shfl(e0v, 0, 16) - cb0;
    int cb1 = __shfl(b1v, 0, 16), cc1 = __shfl(e1v, 0, 16) - cb1;
    int cidx0 = (l16 < (cc0 < 16 ? cc0 : 16)) ? srt[cb0 + l16] : 0;
    int cidx1 = (l16 < (cc1 < 16 ? cc1 : 16)) ? srt[cb1 + l16] : 0;

    for (int r = 0; r <= R_; ++r) {
        __syncthreads();              // b1: previous MFMA reads done; lA/lB free

        // ---- 1. async-stage B chunk r into lB (zero VGPR cost) ----
        {
            const char* srcB = (const char*)BT + (size_t)r * BN * 256;
            #pragma unroll
            for (int j = 0; j < NCOPY; ++j) {
                const char* g = srcB + j * 4096 + wv * 1024 + (lane << 4);
                char* l = (char*)lB + j * 4096 + wv * 1024;
                gload_lds16(g, l);
            }
        }

        // ---- 2. prefetch next chunk's bounds + srt indices ----
        int nb0 = 0, nc0 = 0, nb1 = 0, nc1 = 0, nidx0 = 0, nidx1 = 0;
        if (r + 1 < R_) {
            nb0 = __shfl(b0v, r + 1, 16); nc0 = __shfl(e0v, r + 1, 16) - nb0;
            nb1 = __shfl(b1v, r + 1, 16); nc1 = __shfl(e1v, r + 1, 16) - nb1;
            nidx0 = (l16 < (nc0 < 16 ? nc0 : 16)) ? srt[nb0 + l16] : 0;
            nidx1 = (l16 < (nc1 < 16 ? nc1 : 16)) ? srt[nb1 + l16] : 0;
        }

        // ---- 3. gather chunk r (only feat loads on the chain) ----
        Row8 a0, a1;
        if (r < R_) {
            a0 = gather_idx(featbf, srt, cb0, cc0, cidx0, l16);
            a1 = gather_idx(featbf, srt, cb1, cc1, cidx1, l16);
        } else {
            a0 = row8_zero(); a1 = row8_zero();
            if (row0 < N)
                a0 = row8_add(a0, *(const int4*)(featbf + (size_t)row0 * KCH + l16 * 8));
            if (row1 < N)
                a1 = row8_add(a1, *(const int4*)(featbf + (size_t)row1 * KCH + l16 * 8));
        }

        // ---- 4. write A rows to LDS ----
        {
            int byte0 = ((g16 * BK + l16 * 8) << 1) ^ ((g16 & 15) << 4);
            *(int4*)((char*)lA + byte0) = row8_pack(a0);
            int rowl = 16 + g16;
            int byte1 = ((rowl * BK + l16 * 8) << 1) ^ ((rowl & 15) << 4);
            *(int4*)((char*)lA + byte1) = row8_pack(a1);
        }
        __syncthreads();              // b2: lA published, async B landed (vmcnt drain)

        // ---- 5. MFMA chunk r ----
        #pragma unroll
        for (int kk = 0; kk < BK / 32; ++kk) {
            const int kpos = kk * 32 + (lane >> 4) * 8;
            bf16x8 af[MR], bfr[NR];
            #pragma unroll
            for (int m = 0; m < MR; ++m) {
                int row = m * 16 + (lane & 15);
                af[m] = *(const bf16x8*)((const char*)lA +
                         (((row * BK + kpos) << 1) ^ ((row & 15) << 4)));
            }
            #pragma unroll
            for (int n = 0; n < NR; ++n) {
                int col = wv * WN + n * 16 + (lane & 15);
                bfr[n] = *(const bf16x8*)((const char*)lB +
                         (((col * BK + kpos) << 1) ^ ((col & 15) << 4)));
            }
            #pragma unroll
            for (int m = 0; m < MR; ++m)
                #pragma unroll
                for (int n = 0; n < NR; ++n)
                    acc[m][n] = __builtin_amdgcn_mfma_f32_16x16x32_bf16(
                        af[m], bfr[n], acc[m][n], 0, 0, 0);
        }

        // ---- 6. rotate prefetched index state ----
        cb0 = nb0; cc0 = nc0; cidx0 = nidx0;
        cb1 = nb1; cc1 = nc1; cidx1 = nidx1;
    }

    // ---- epilogue: C/D layout row=(lane>>4)*4+i, col=lane&15 ----
    #pragma unroll
    for (int m = 0; m < MR; ++m)
        #pragma unroll
        for (int n = 0; n < NR; ++n)
            #pragma unroll
            for (int i = 0; i < 4; ++i) {
                int row  = m * 16 + ((lane >> 4) << 2) + i;
                int col  = wv * WN + n * 16 + (lane & 15);
                int grow = n0 + row;
                if (grow >= N) continue;
                float v = acc[m][n][i] + bias[col];
                if (relu) v = fmaxf(v, 0.f);
                if (OUTBF) ((short*)Hout)[(size_t)grow * BN + col] = f2bf(v);
                else       ((float*)Hout)[(size_t)grow * BN + col] = v;
            }
}

// ------- classifier MFMA GEMM: out[n][a] = h2[n][:] @ wcT[a][:] + bc[a] -------
__global__ __launch_bounds__(256)
void classifier_gemm_kernel(const short* __restrict__ h2bf,   // [N][64] bf16
                            const short* __restrict__ wcT,    // [400][64] bf16
                            const float* __restrict__ bc,
                            float* __restrict__ out, int N)
{
    constexpr int BM = 128, BN = 80, BK = 64;
    constexpr int MR = 2, NR = 5;

    __shared__ short lA[BM * BK];
    __shared__ short lB[BN * BK];

    const int tid  = threadIdx.x;
    const int lane = tid & 63;
    const int wv   = tid >> 6;
    const int nodeBase = blockIdx.x * BM;
    const int colBase  = blockIdx.y * BN;

    const int t8  = tid & 7;
    const int r32 = tid >> 3;

    #pragma unroll
    for (int it = 0; it < 4; ++it) {
        int row  = it * 32 + r32;
        int grow = nodeBase + row;
        int4 v = {0, 0, 0, 0};
        if (grow < N) v = *(const int4*)(h2bf + (size_t)grow * DOUT2 + t8 * 8);
        int byte = ((row * BK + t8 * 8) << 1) ^ ((row & 7) << 4);
        *(int4*)((char*)lA + byte) = v;
    }
    for (int o = r32; o < BN; o += 32) {
        int4 v = *(const int4*)(wcT + (size_t)(colBase + o) * DOUT2 + t8 * 8);
        int byte = ((o * BK + t8 * 8) << 1) ^ ((o & 7) << 4);
        *(int4*)((char*)lB + byte) = v;
    }
    __syncthreads();

    f32x4 acc[MR][NR];
    #pragma unroll
    for (int m = 0; m < MR; ++m)
        #pragma unroll
        for (int n = 0; n < NR; ++n)
            acc[m][n] = (f32x4){0.f, 0.f, 0.f, 0.f};

    #pragma unroll
    for (int kk = 0; kk < BK / 32; ++kk) {
        const int kpos = kk * 32 + (lane >> 4) * 8;
        bf16x8 af[MR], bfr[NR];
        #pragma unroll
        for (int m = 0; m < MR; ++m) {
            int row = wv * 32 + m * 16 + (lane & 15);
            af[m] = *(const bf16x8*)((const char*)lA +
                     (((row * BK + kpos) << 1) ^ ((row & 7) << 4)));
        }
        #pragma unroll
        for (int n = 0; n < NR; ++n) {
            int col = n * 16 + (lane & 15);
            bfr[n] = *(const bf16x8*)((const char*)lB +
                     (((col * BK + kpos) << 1) ^ ((col & 7) << 4)));
        }
        #pragma unroll
        for (int m = 0; m < MR; ++m)
            #pragma unroll
            for (int n = 0; n < NR; ++n)
                acc[m][n] = __builtin_amdgcn_mfma_f32_16x16x32_bf16(
                    af[m], bfr[n], acc[m][n], 0, 0, 0);
    }

    #pragma unroll
    for (int m = 0; m < MR; ++m)
        #pragma unroll
        for (int n = 0; n < NR; ++n)
            #pragma unroll
            for (int i = 0; i < 4; ++i) {
                int row  = wv * 32 + m * 16 + ((lane >> 4) << 2) + i;
                int col  = n * 16 + (lane & 15);
                int grow = nodeBase + row;
                if (grow >= N) continue;
                int gcol = colBase + col;
                out[(size_t)grow * DADR + gcol] = acc[m][n][i] + bc[gcol];
            }
}

static inline size_t align16(size_t x) { return (x + 15) & ~(size_t)15; }

extern "C" void kernel_launch(void* const* d_in, const int* in_sizes, int n_in,
                              void* d_out, int out_size, void* d_ws, size_t ws_size,
                              hipStream_t stream) {
    const float* x      = (const float*)d_in[0];
    const int*   ei     = (const int*)d_in[1];
    const int*   et     = (const int*)d_in[2];
    const float* comp1  = (const float*)d_in[3];
    const float* basis1 = (const float*)d_in[4];
    const float* root1  = (const float*)d_in[5];
    const float* bias1  = (const float*)d_in[6];
    const float* comp2  = (const float*)d_in[7];
    const float* basis2 = (const float*)d_in[8];
    const float* root2  = (const float*)d_in[9];
    const float* bias2  = (const float*)d_in[10];
    const float* wc     = (const float*)d_in[11];
    const float* bc     = (const float*)d_in[12];
    float* out = (float*)d_out;

    const int E = in_sizes[1] / 2;
    const int N = in_sizes[0] / DIN1;
    const int* srcp = ei;
    const int* dstp = ei + E;

    const int NSEG = N * R_;
    const int NBLK = (NSEG + SCAN_CHUNK - 1) / SCAN_CHUNK;

    char* ws = (char*)d_ws;
    size_t o = 0;
    int*   cntI   = (int*)(ws + o);   o = align16(o + (size_t)NSEG * 4);
    int*   off2   = (int*)(ws + o);   o = align16(o + (size_t)(NSEG + 1) * 4);
    int*   cursor = (int*)(ws + o);   o = align16(o + (size_t)NSEG * 4);
    int*   bsum   = (int*)(ws + o);   o = align16(o + (size_t)NBLK * 4);
    int*   boff   = (int*)(ws + o);   o = align16(o + (size_t)NBLK * 4);
    int*   srt    = (int*)(ws + o);   o = align16(o + (size_t)E * 4);
    short* BT1    = (short*)(ws + o); o = align16(o + (size_t)(R_ + 1) * DHID * 128 * 2);
    short* BT2    = (short*)(ws + o); o = align16(o + (size_t)(R_ + 1) * DOUT2 * 128 * 2);
    short* wcTb   = (short*)(ws + o); o = align16(o + (size_t)DADR * DOUT2 * 2);
    short* xbf    = (short*)(ws + o); o = align16(o + (size_t)N * DIN1 * 2);
    short* h1bf   = (short*)(ws + o); o = align16(o + (size_t)N * DHID * 2);
    short* h2bf   = (short*)(ws + o); o = align16(o + (size_t)N * DOUT2 * 2);

    // ---- fused setup: tobf + counts + weight prep ----
    const int n4 = N * DIN1 / 4;
    hipMemsetAsync(cntI, 0, (size_t)NSEG * 4, stream);
    {
        long long total = (long long)n4 + E + PREP5;
        int grid = (int)((total + 255) / 256);
        setup_kernel<<<grid, 256, 0, stream>>>(x, xbf, n4, dstp, et, cntI, E, N,
                                               comp1, basis1, root1,
                                               comp2, basis2, root2, wc,
                                               BT1, BT2, wcTb);
    }

    // ---- CSR scan + reorder ----
    scan_bsum_kernel<<<NBLK, 256, 0, stream>>>(cntI, NSEG, bsum);
    scan_top_kernel<<<1, 256, 0, stream>>>(bsum, NBLK, boff, off2, NSEG);
    scan_final_kernel<<<NBLK, 256, 0, stream>>>(cntI, NSEG, boff, off2, cursor);
    reorder_kernel<<<(E + 255) / 256, 256, 0, stream>>>(srcp, dstp, et, cursor, srt, E, N);

    // ---- two fused RGCN layers ----
    const int gGrid = (N + 31) / 32;
    rgcn_fused_kernel<DHID, true><<<gGrid, 256, 0, stream>>>(xbf,  off2, srt, BT1, bias1, h1bf, N, 1);
    rgcn_fused_kernel<DOUT2, true><<<gGrid, 256, 0, stream>>>(h1bf, off2, srt, BT2, bias2, h2bf, N, 0);

    // ---- classifier (MFMA) ----
    dim3 cGrid((N + 127) / 128, DADR / 80);
    classifier_gemm_kernel<<<cGrid, 256, 0, stream>>>(h2bf, wcTb, bc, out, N);
}